// Round 6
// baseline (440.307 us; speedup 1.0000x reference)
//
#include <hip/hip_runtime.h>
#include <float.h>
#include <limits.h>

#define RADIUS 0.05f
#define TH     3.0f      // N(0,1) tail: per-batch mean ~1350 hits; 64th-largest of 1M ~ 3.8
#define LCAP   1024      // per-block LDS hit buffer (mean ~88 at gx=16)
#define SORTN  2048      // per-batch sort size (mean 1350, sd 37 -> +19 sigma margin)

typedef unsigned long long u64;

__device__ __forceinline__ unsigned fkey(float f) {
  unsigned u = __float_as_uint(f);
  return (u & 0x80000000u) ? ~u : (u | 0x80000000u);  // monotonic float->uint
}

__global__ __launch_bounds__(256) void zero_k(unsigned* cnt, int* bad, int B) {
  int t = blockIdx.x * blockDim.x + threadIdx.x;
  if (t < B * 16) cnt[t] = 0u;          // counters padded to 64B lines (stride 16 u32)
  if (t < B) bad[t] = 0;
}

__global__ __launch_bounds__(256) void scan_collect(
    const float* __restrict__ hm, unsigned* __restrict__ cnt, int* __restrict__ bad,
    u64* __restrict__ buf, int bcap, int elems, int chunk) {
  const int b   = blockIdx.y;
  const int tid = threadIdx.x;
  const int vbase = blockIdx.x * chunk;                 // in float4 units
  const float4* p = (const float4*)(hm + (size_t)b * elems) + vbase;

  __shared__ u64 sbuf[LCAP];
  __shared__ unsigned sh, sbase;
  if (tid == 0) sh = 0u;
  __syncthreads();

  auto push = [&](float v, int idx) {
    if (v > TH) {                                       // v>3 => positive => fkey = u|signbit
      unsigned pos = atomicAdd(&sh, 1u);                // LDS atomic: cheap, no XCD traffic
      if (pos < LCAP)
        sbuf[pos] = ((u64)(__float_as_uint(v) | 0x80000000u) << 32) | (unsigned)(~idx);
    }
  };

  int chunkMain = chunk & ~1023;                        // 4 float4 loads in flight per thread
  for (int i = tid; i < chunkMain; i += 1024) {
    float4 v0 = p[i];
    float4 v1 = p[i + 256];
    float4 v2 = p[i + 512];
    float4 v3 = p[i + 768];
    // branch-free filter: one 16-way max (v_max3 chains) + one compare per 16 elems
    float m0 = fmaxf(fmaxf(v0.x, v0.y), fmaxf(v0.z, v0.w));
    float m1 = fmaxf(fmaxf(v1.x, v1.y), fmaxf(v1.z, v1.w));
    float m2 = fmaxf(fmaxf(v2.x, v2.y), fmaxf(v2.z, v2.w));
    float m3 = fmaxf(fmaxf(v3.x, v3.y), fmaxf(v3.z, v3.w));
    float mm = fmaxf(fmaxf(m0, m1), fmaxf(m2, m3));
    if (mm > TH) {                                      // ~2% of lanes enter
      int g0 = (vbase + i) << 2, g1 = (vbase + i + 256) << 2;
      int g2 = (vbase + i + 512) << 2, g3 = (vbase + i + 768) << 2;
      push(v0.x, g0); push(v0.y, g0 + 1); push(v0.z, g0 + 2); push(v0.w, g0 + 3);
      push(v1.x, g1); push(v1.y, g1 + 1); push(v1.z, g1 + 2); push(v1.w, g1 + 3);
      push(v2.x, g2); push(v2.y, g2 + 1); push(v2.z, g2 + 2); push(v2.w, g2 + 3);
      push(v3.x, g3); push(v3.y, g3 + 1); push(v3.z, g3 + 2); push(v3.w, g3 + 3);
    }
  }
  for (int i = chunkMain + tid; i < chunk; i += 256) {  // tail (empty for 1024x1024)
    float4 v = p[i];
    int g = (vbase + i) << 2;
    push(v.x, g); push(v.y, g + 1); push(v.z, g + 2); push(v.w, g + 3);
  }

  __syncthreads();
  unsigned h = sh;
  unsigned stored = h < (unsigned)LCAP ? h : (unsigned)LCAP;
  if (tid == 0) {
    sbase = atomicAdd(&cnt[b * 16], stored);            // ONE global atomic per block
    if (h > (unsigned)LCAP || sbase + stored > (unsigned)bcap) atomicExch(&bad[b], 1);
  }
  __syncthreads();
  unsigned gb = sbase;
  for (unsigned i = tid; i < stored; i += 256) {
    unsigned dst = gb + i;
    if (dst < (unsigned)bcap) buf[(size_t)b * bcap + dst] = sbuf[i];
  }
}

__global__ __launch_bounds__(256) void select_k(
    const float* __restrict__ hm, const unsigned* __restrict__ cnt,
    const int* __restrict__ bad, const u64* __restrict__ buf, int bcap,
    float* __restrict__ out, int W, int H, int K, int nk, int elems) {
  const int b = blockIdx.x, tid = threadIdx.x;

  __shared__ u64 s[SORTN];
  __shared__ unsigned s_cnt;
  __shared__ int s_m;
  __shared__ float topx[64], topy[64];
  __shared__ float outbuf[128];

  int c = 0;
  bool good = false;
  if (bcap > 0) {
    c = (int)cnt[b * 16];
    good = (!bad[b]) && (c >= K) && (c <= bcap) && (c <= SORTN);
  }

  if (good) {
    for (int i = tid; i < SORTN; i += 256)
      s[i] = (i < c) ? buf[(size_t)b * bcap + i] : 0ull;
  } else {
    // ---- exact data-agnostic fallback: binary search K-th key over whole image ----
    unsigned lo = 0u, hi = 0xFFFFFFFFu;
    const float4* p4 = (const float4*)(hm + (size_t)b * elems);
    const int nvec4 = elems >> 2;
    while (lo < hi) {
      unsigned mid = lo + ((hi - lo) >> 1) + 1u;
      if (tid == 0) s_cnt = 0u;
      __syncthreads();
      unsigned local = 0;
      for (int i = tid; i < nvec4; i += 256) {
        float4 v = p4[i];
        local += (fkey(v.x) >= mid) + (fkey(v.y) >= mid) + (fkey(v.z) >= mid) + (fkey(v.w) >= mid);
      }
      atomicAdd(&s_cnt, local);
      __syncthreads();
      if (s_cnt >= (unsigned)K) lo = mid; else hi = mid - 1u;
      __syncthreads();
    }
    if (tid == 0) s_m = 0;
    __syncthreads();
    const float* q = hm + (size_t)b * elems;
    for (int i = tid; i < elems; i += 256) {
      unsigned kk = fkey(q[i]);
      if (kk >= lo) {
        int pos = atomicAdd(&s_m, 1);
        if (pos < SORTN) s[pos] = ((u64)kk << 32) | (unsigned)(~i);
      }
    }
    __syncthreads();
    int c2 = s_m < SORTN ? s_m : SORTN;
    for (int i = tid; i < SORTN; i += 256)
      if (i >= c2) s[i] = 0ull;
  }
  __syncthreads();

  // ---- bitonic sort descending on packed (fkey | ~idx): val desc, idx asc ----
  for (int k2 = 2; k2 <= SORTN; k2 <<= 1) {
    for (int j = k2 >> 1; j > 0; j >>= 1) {
      for (int i = tid; i < SORTN; i += 256) {
        int ix = i ^ j;
        if (ix > i) {
          u64 a = s[i], bb = s[ix];
          bool desc = ((i & k2) == 0);
          bool sw = desc ? (a < bb) : (a > bb);
          if (sw) { s[i] = bb; s[ix] = a; }
        }
      }
      __syncthreads();
    }
  }

  // ---- decode top-K coords ----
  const float invW = 1.0f / (float)(W - 1);
  const float invH = 1.0f / (float)(H - 1);
  if (tid < K) {
    u64 e = s[tid];
    int idx = (int)(~(unsigned)(e & 0xFFFFFFFFu));
    int ty = idx / W;
    int tx = idx - ty * W;
    topx[tid] = (float)tx * invW;
    topy[tid] = (float)ty * invH;
  }
  for (int i = tid; i < 2 * nk; i += 256) outbuf[i] = 0.0f;
  __syncthreads();

  // ---- single-wave greedy NMS (K <= 64): ballot/shfl, zero barriers ----
  if (tid < 64) {
    float myx = (tid < K) ? topx[tid] : 0.0f;
    float myy = (tid < K) ? topy[tid] : 0.0f;
    bool sel = false;
    int cntA = 0;
    for (int i = 0; i < K; i++) {
      float xi = __shfl(myx, i);
      float yi = __shfl(myy, i);
      float dx = myx - xi, dy = myy - yi;
      bool close = sel && (sqrtf(dx * dx + dy * dy) < RADIUS);
      u64 anym = __ballot(close);
      bool accept = (anym == 0ull) && (cntA < nk);
      if (tid == i) sel = accept;
      cntA += accept ? 1 : 0;
    }
    u64 selball = __ballot(sel);
    if (sel) {
      int slot = __popcll(selball & ((1ull << tid) - 1ull));  // score-order compaction
      if (slot < nk) { outbuf[2 * slot] = myx; outbuf[2 * slot + 1] = myy; }
    }
  }
  __syncthreads();

  float* outp = out + (size_t)b * 2 * nk;
  for (int i = tid; i < 2 * nk; i += 256) outp[i] = outbuf[i];
}

extern "C" void kernel_launch(void* const* d_in, const int* in_sizes, int n_in,
                              void* d_out, int out_size, void* d_ws, size_t ws_size,
                              hipStream_t stream) {
  const float* hm = (const float*)d_in[0];
  const int H = 1024, W = 1024;
  const int elems = H * W;
  int B = in_sizes[0] / elems;              // 64
  int nk = out_size / (B * 2);              // 16
  int K = 4 * nk;                           // 64
  if (K > elems) K = elems;
  if (K > 64) K = 64;                       // single-wave NMS bound (problem: K=64)

  // ws layout: cnt B*16 u32 (padded lines) | bad B int | buf B*bcap u64
  unsigned* cnt = (unsigned*)d_ws;
  size_t off_bad = (size_t)B * 16 * sizeof(unsigned);
  int* bad = (int*)((char*)d_ws + off_bad);
  size_t off_buf = (off_bad + (size_t)B * sizeof(int) + 255) & ~(size_t)255;
  u64* buf = (u64*)((char*)d_ws + off_buf);
  int bcap = 0;
  if (ws_size > off_buf) {
    size_t avail = ws_size - off_buf;
    long long capl = (long long)(avail / ((size_t)B * sizeof(u64)));
    bcap = (capl > SORTN) ? SORTN : (int)capl;
  }

  zero_k<<<(B * 16 + 255) / 256, 256, 0, stream>>>(cnt, bad, B);
  if (bcap > 0) {
    const int gx = 16;                      // match known-good R2 geometry exactly
    int chunk = (elems >> 2) / gx;          // 16384 float4 per block
    dim3 grid(gx, B);
    scan_collect<<<grid, 256, 0, stream>>>(hm, cnt, bad, buf, bcap, elems, chunk);
  }
  select_k<<<B, 256, 0, stream>>>(hm, cnt, bad, buf, bcap, (float*)d_out, W, H, K, nk, elems);
}